// Round 6
// baseline (23.020 us; speedup 1.0000x reference)
//
#include <hip/hip_runtime.h>
#include <hip/hip_bf16.h>

#define EPS 1e-07f

#define BLOCK 256
#define IPT   4             // rays per thread
#define SLICE 64            // Gaussians per K-slice (grid.y); multiple of 4

// sqrt(0.5*log2(e)) ; log2(sqrt(2*pi))
#define SQRT_HALF_LOG2E 0.84932180028801904f
#define LOG2_SQRT_2PI   1.32574806473616588f

typedef float v4f __attribute__((ext_vector_type(4)));

// ---------------------------------------------------------------------------
// Kernel 1: per-Gaussian precompute (K threads) + zero d_out.
// Cross-product identity: c0 - b^2/a = (u x (p-pos))^2 / a',  a' = u^T(S/detS)u
// gF row-major [6][K]:
//   row 0..2 : m00' m01' m11'  (S/detS)
//   row 3    : cc = log2(conc) + log2(sqrt(2pi)) - 0.5*log2(detS)
//   row 4..5 : pos0 pos1
// ---------------------------------------------------------------------------
__global__ void precompute_gauss(const float* __restrict__ pos_raw,
                                 const float* __restrict__ conc_raw,
                                 const float* __restrict__ scale_raw,
                                 const float* __restrict__ rot_raw,
                                 const void*  __restrict__ map_size_p,
                                 float* __restrict__ gF,
                                 float* __restrict__ out,
                                 int K, int R)
{
    int k = blockIdx.x * blockDim.x + threadIdx.x;
    int nthreads = gridDim.x * blockDim.x;

    // Zero the output (ordered before splat_main on the same stream).
    for (int i = k; i < R; i += nthreads) out[i] = 0.0f;

    if (k >= K) return;

    // map_size may arrive as int32 or float32 single-element array.
    unsigned int msbits = *(const unsigned int*)map_size_p;
    float msf = __uint_as_float(msbits);
    float ms;
    if (msf >= 1e-3f && msf <= 1e9f) ms = msf;
    else                             ms = (float)(*(const int*)map_size_p);

    float pr0 = pos_raw[2*k],  pr1 = pos_raw[2*k+1];
    float pos0 = ms / (1.0f + expf(-pr0));   // sigmoid * map_size
    float pos1 = ms / (1.0f + expf(-pr1));

    float cr = conc_raw[k];
    float conc = fmaxf(cr, 0.0f) + log1pf(expf(-fabsf(cr)));   // stable softplus

    float s0 = expf(scale_raw[2*k]);
    float s1 = expf(scale_raw[2*k+1]);
    float d0 = 1.0f / (s0*s0 + EPS);
    float d1 = 1.0f / (s1*s1 + EPS);

    float rot = rot_raw[k];
    float c = cosf(rot), s = sinf(rot);

    float m00 = c*c*d0 + s*s*d1;
    float m01 = c*s*(d0 - d1);
    float m11 = s*s*d0 + c*c*d1;

    float det    = d0 * d1;            // detS
    float invdet = 1.0f / det;

    float cc = log2f(conc) + LOG2_SQRT_2PI - 0.5f * log2f(det);

    gF[0*K + k] = m00 * invdet;
    gF[1*K + k] = m01 * invdet;
    gF[2*K + k] = m11 * invdet;
    gF[3*K + k] = cc;
    gF[4*K + k] = pos0;
    gF[5*K + k] = pos1;
}

// ---------------------------------------------------------------------------
// Kernel 2: main pairwise accumulation, IPT rays per thread.
//   t   = (w~ + u~1*pos0 - u~0*pos1) * rsqrt(a')
//   out+= rsqrt(a') * 2^( cc - t^2 )
// One 6x ds_read_b128 group (4 Gaussians) feeds 4*IPT = 16 pair-computations.
// ---------------------------------------------------------------------------
__global__ __launch_bounds__(BLOCK) void splat_main(
        const float* __restrict__ p_rays,
        const float* __restrict__ u_rays,
        const float* __restrict__ gF,
        float* __restrict__ out,
        int K)
{
    __shared__ float sF[6][SLICE];

    const int k0 = blockIdx.y * SLICE;
    const int nk = min(SLICE, K - k0);

    // Stage the slice, SoA rows.
    for (int i = threadIdx.x; i < 6*SLICE; i += BLOCK) {
        int f = i >> 6;             // SLICE == 64
        int c = i & (SLICE - 1);
        if (c < nk) sF[f][c] = gF[f*K + k0 + c];
    }
    __syncthreads();

    const int rbase = blockIdx.x * (BLOCK * IPT) + threadIdx.x;

    float qu0[IPT], qu1[IPT], qu2[IPT], wt[IPT], su1[IPT], nsu0[IPT], acc[IPT];
    #pragma unroll
    for (int r = 0; r < IPT; ++r) {
        int ray = rbase + r * BLOCK;
        float2 p2 = *(const float2*)(p_rays + 2*ray);
        float2 u2 = *(const float2*)(u_rays + 2*ray);
        float p0 = p2.x, p1 = p2.y, u0 = u2.x, u1 = u2.y;
        qu0[r]  = u0*u0;
        qu1[r]  = 2.0f*u0*u1;
        qu2[r]  = u1*u1;
        wt[r]   =  SQRT_HALF_LOG2E * (u0*p1 - u1*p0);
        su1[r]  =  SQRT_HALF_LOG2E * u1;
        nsu0[r] = -SQRT_HALF_LOG2E * u0;
        acc[r]  = 0.0f;
    }

    const int nk4 = nk & ~3;
    for (int t4 = 0; t4 < nk4; t4 += 4) {
        v4f M00 = *(const v4f*)&sF[0][t4];   // uniform address -> broadcast
        v4f M01 = *(const v4f*)&sF[1][t4];
        v4f M11 = *(const v4f*)&sF[2][t4];
        v4f CC  = *(const v4f*)&sF[3][t4];
        v4f P0  = *(const v4f*)&sF[4][t4];
        v4f P1  = *(const v4f*)&sF[5][t4];

        #pragma unroll
        for (int g = 0; g < 4; ++g) {
            #pragma unroll
            for (int r = 0; r < IPT; ++r) {
                float a  = fmaf(qu2[r], M11[g], fmaf(qu1[r], M01[g], qu0[r] * M00[g]));
                float cr = fmaf(nsu0[r], P1[g], fmaf(su1[r], P0[g], wt[r]));
                float ra = __builtin_amdgcn_rsqf(a);
                float t  = cr * ra;
                float ar = fmaf(-t, t, CC[g]);
                float e  = __builtin_amdgcn_exp2f(ar);
                acc[r] = fmaf(ra, e, acc[r]);
            }
        }
    }
    // tail (not taken for K % SLICE == 0)
    for (int j = nk4; j < nk; ++j) {
        #pragma unroll
        for (int r = 0; r < IPT; ++r) {
            float a  = fmaf(qu2[r], sF[2][j], fmaf(qu1[r], sF[1][j], qu0[r] * sF[0][j]));
            float cr = fmaf(nsu0[r], sF[5][j], fmaf(su1[r], sF[4][j], wt[r]));
            float ra = __builtin_amdgcn_rsqf(a);
            float t  = cr * ra;
            float ar = fmaf(-t, t, sF[3][j]);
            float e  = __builtin_amdgcn_exp2f(ar);
            acc[r] = fmaf(ra, e, acc[r]);
        }
    }

    #pragma unroll
    for (int r = 0; r < IPT; ++r)
        atomicAdd(&out[rbase + r * BLOCK], acc[r]);
}

// ---------------------------------------------------------------------------
extern "C" void kernel_launch(void* const* d_in, const int* in_sizes, int n_in,
                              void* d_out, int out_size, void* d_ws, size_t ws_size,
                              hipStream_t stream)
{
    const float* pos_raw   = (const float*)d_in[0];
    const float* conc_raw  = (const float*)d_in[1];
    const float* scale_raw = (const float*)d_in[2];
    const float* rot_raw   = (const float*)d_in[3];
    const float* p_rays    = (const float*)d_in[4];
    const float* u_rays    = (const float*)d_in[5];
    const void*  map_size  = d_in[6];

    const int K = in_sizes[1];          // conc_raw is (K,)
    const int R = out_size;             // output is (R,)

    float* out = (float*)d_out;
    float* gF  = (float*)d_ws;          // 6*K floats

    {
        dim3 grid((K + BLOCK - 1) / BLOCK);
        precompute_gauss<<<grid, BLOCK, 0, stream>>>(pos_raw, conc_raw, scale_raw,
                                                     rot_raw, map_size,
                                                     gF, out, K, R);
    }
    {
        dim3 grid(R / (BLOCK * IPT), (K + SLICE - 1) / SLICE);
        splat_main<<<grid, BLOCK, 0, stream>>>(p_rays, u_rays, gF, out, K);
    }
}

// Round 7
// 22.233 us; speedup vs baseline: 1.0354x; 1.0354x over previous
//
#include <hip/hip_runtime.h>
#include <hip/hip_bf16.h>

#define EPS 1e-07f

#define BLOCK 256
#define IPT   2             // rays per thread
#define SLICE 64            // Gaussians per K-slice; multiple of 4
#define PBLOCK 64           // precompute block size

// sqrt(0.5*log2(e)) ; log2(sqrt(2*pi))
#define SQRT_HALF_LOG2E 0.84932180028801904f
#define LOG2_SQRT_2PI   1.32574806473616588f

typedef float v4f __attribute__((ext_vector_type(4)));

// ---------------------------------------------------------------------------
// Kernel 1: per-Gaussian precompute (K threads over 64 blocks) + zero d_out.
// Cross-product identity: c0 - b^2/a = (u x (p-pos))^2 / a',  a' = u^T(S/detS)u
// gF row-major [6][K]: {m00', m01', m11', cc, pos0, pos1}
//   cc = log2(conc) + log2(sqrt(2pi)) - 0.5*log2(detS)
// Hardware trans intrinsics (__expf/__logf/__cosf/__sinf) to shorten the
// serial chain; precision ~1e-6 rel, far inside the test threshold.
// ---------------------------------------------------------------------------
__global__ __launch_bounds__(PBLOCK) void precompute_gauss(
                                 const float* __restrict__ pos_raw,
                                 const float* __restrict__ conc_raw,
                                 const float* __restrict__ scale_raw,
                                 const float* __restrict__ rot_raw,
                                 const void*  __restrict__ map_size_p,
                                 float* __restrict__ gF,
                                 float* __restrict__ out,
                                 int K, int R)
{
    int k = blockIdx.x * blockDim.x + threadIdx.x;
    int nthreads = gridDim.x * blockDim.x;

    // Zero the output (ordered before splat_main on the same stream).
    for (int i = k; i < R; i += nthreads) out[i] = 0.0f;

    if (k >= K) return;

    // map_size may arrive as int32 or float32 single-element array.
    unsigned int msbits = *(const unsigned int*)map_size_p;
    float msf = __uint_as_float(msbits);
    float ms;
    if (msf >= 1e-3f && msf <= 1e9f) ms = msf;
    else                             ms = (float)(*(const int*)map_size_p);

    float pr0 = pos_raw[2*k],  pr1 = pos_raw[2*k+1];
    float pos0 = ms / (1.0f + __expf(-pr0));   // sigmoid * map_size
    float pos1 = ms / (1.0f + __expf(-pr1));

    float cr = conc_raw[k];
    float conc = fmaxf(cr, 0.0f) + __logf(1.0f + __expf(-fabsf(cr)));  // softplus

    float s0 = __expf(scale_raw[2*k]);
    float s1 = __expf(scale_raw[2*k+1]);
    float d0 = 1.0f / (s0*s0 + EPS);
    float d1 = 1.0f / (s1*s1 + EPS);

    float rot = rot_raw[k];
    float c = __cosf(rot), s = __sinf(rot);

    float m00 = c*c*d0 + s*s*d1;
    float m01 = c*s*(d0 - d1);
    float m11 = s*s*d0 + c*c*d1;

    float det    = d0 * d1;            // detS
    float invdet = 1.0f / det;

    float cc = __log2f(conc) + LOG2_SQRT_2PI - 0.5f * __log2f(det);

    gF[0*K + k] = m00 * invdet;
    gF[1*K + k] = m01 * invdet;
    gF[2*K + k] = m11 * invdet;
    gF[3*K + k] = cc;
    gF[4*K + k] = pos0;
    gF[5*K + k] = pos1;
}

// ---------------------------------------------------------------------------
// Kernel 2: main pairwise accumulation, IPT=2 rays per thread.
//   t   = (w~ + u~1*pos0 - u~0*pos1) * rsqrt(a')
//   out+= rsqrt(a') * 2^( cc - t^2 )
// LDS layout: sG[group][6][4] — each 4-Gaussian group's six v4fs contiguous.
// Fast path (nk == SLICE): fully unrolled 16 groups, no branches.
// ---------------------------------------------------------------------------
__global__ __launch_bounds__(BLOCK) void splat_main(
        const float* __restrict__ p_rays,
        const float* __restrict__ u_rays,
        const float* __restrict__ gF,
        float* __restrict__ out,
        int K)
{
    __shared__ float sG[SLICE/4][6][4];

    const int k0 = blockIdx.y * SLICE;
    const int nk = min(SLICE, K - k0);

    // Stage the slice: global side coalesced per row, LDS side group-packed.
    for (int i = threadIdx.x; i < 6*SLICE; i += BLOCK) {
        int f = i >> 6;              // SLICE == 64
        int c = i & (SLICE - 1);
        if (c < nk) sG[c >> 2][f][c & 3] = gF[f*K + k0 + c];
    }
    __syncthreads();

    const int rbase = blockIdx.x * (BLOCK * IPT) + threadIdx.x;

    float qu0[IPT], qu1[IPT], qu2[IPT], wt[IPT], su1[IPT], nsu0[IPT], acc[IPT];
    #pragma unroll
    for (int r = 0; r < IPT; ++r) {
        int ray = rbase + r * BLOCK;
        float2 p2 = *(const float2*)(p_rays + 2*ray);
        float2 u2 = *(const float2*)(u_rays + 2*ray);
        float p0 = p2.x, p1 = p2.y, u0 = u2.x, u1 = u2.y;
        qu0[r]  = u0*u0;
        qu1[r]  = 2.0f*u0*u1;
        qu2[r]  = u1*u1;
        wt[r]   =  SQRT_HALF_LOG2E * (u0*p1 - u1*p0);
        su1[r]  =  SQRT_HALF_LOG2E * u1;
        nsu0[r] = -SQRT_HALF_LOG2E * u0;
        acc[r]  = 0.0f;
    }

#define PAIR_BODY(M00, M01, M11, CC, P0, P1, g, r)                              \
    {                                                                           \
        float a_  = fmaf(qu2[r], (M11)[g], fmaf(qu1[r], (M01)[g],               \
                                                qu0[r] * (M00)[g]));            \
        float cr_ = fmaf(nsu0[r], (P1)[g], fmaf(su1[r], (P0)[g], wt[r]));       \
        float ra_ = __builtin_amdgcn_rsqf(a_);                                  \
        float t_  = cr_ * ra_;                                                  \
        float ar_ = fmaf(-t_, t_, (CC)[g]);                                     \
        float e_  = __builtin_amdgcn_exp2f(ar_);                                \
        acc[r] = fmaf(ra_, e_, acc[r]);                                         \
    }

    if (nk == SLICE) {
        // Fast path: full unroll, 16 groups, no branches.
        #pragma unroll
        for (int t4 = 0; t4 < SLICE/4; ++t4) {
            v4f M00 = *(const v4f*)&sG[t4][0][0];
            v4f M01 = *(const v4f*)&sG[t4][1][0];
            v4f M11 = *(const v4f*)&sG[t4][2][0];
            v4f CC  = *(const v4f*)&sG[t4][3][0];
            v4f P0  = *(const v4f*)&sG[t4][4][0];
            v4f P1  = *(const v4f*)&sG[t4][5][0];
            #pragma unroll
            for (int g = 0; g < 4; ++g)
                #pragma unroll
                for (int r = 0; r < IPT; ++r)
                    PAIR_BODY(M00, M01, M11, CC, P0, P1, g, r)
        }
    } else {
        const int ng = nk >> 2;
        for (int t4 = 0; t4 < ng; ++t4) {
            v4f M00 = *(const v4f*)&sG[t4][0][0];
            v4f M01 = *(const v4f*)&sG[t4][1][0];
            v4f M11 = *(const v4f*)&sG[t4][2][0];
            v4f CC  = *(const v4f*)&sG[t4][3][0];
            v4f P0  = *(const v4f*)&sG[t4][4][0];
            v4f P1  = *(const v4f*)&sG[t4][5][0];
            #pragma unroll
            for (int g = 0; g < 4; ++g)
                #pragma unroll
                for (int r = 0; r < IPT; ++r)
                    PAIR_BODY(M00, M01, M11, CC, P0, P1, g, r)
        }
        for (int j = ng << 2; j < nk; ++j) {
            int t4 = j >> 2, g = j & 3;
            #pragma unroll
            for (int r = 0; r < IPT; ++r) {
                float a  = fmaf(qu2[r], sG[t4][2][g], fmaf(qu1[r], sG[t4][1][g],
                                                           qu0[r] * sG[t4][0][g]));
                float cr = fmaf(nsu0[r], sG[t4][5][g], fmaf(su1[r], sG[t4][4][g], wt[r]));
                float ra = __builtin_amdgcn_rsqf(a);
                float t  = cr * ra;
                float ar = fmaf(-t, t, sG[t4][3][g]);
                float e  = __builtin_amdgcn_exp2f(ar);
                acc[r] = fmaf(ra, e, acc[r]);
            }
        }
    }
#undef PAIR_BODY

    #pragma unroll
    for (int r = 0; r < IPT; ++r)
        atomicAdd(&out[rbase + r * BLOCK], acc[r]);
}

// ---------------------------------------------------------------------------
extern "C" void kernel_launch(void* const* d_in, const int* in_sizes, int n_in,
                              void* d_out, int out_size, void* d_ws, size_t ws_size,
                              hipStream_t stream)
{
    const float* pos_raw   = (const float*)d_in[0];
    const float* conc_raw  = (const float*)d_in[1];
    const float* scale_raw = (const float*)d_in[2];
    const float* rot_raw   = (const float*)d_in[3];
    const float* p_rays    = (const float*)d_in[4];
    const float* u_rays    = (const float*)d_in[5];
    const void*  map_size  = d_in[6];

    const int K = in_sizes[1];          // conc_raw is (K,)
    const int R = out_size;             // output is (R,)

    float* out = (float*)d_out;
    float* gF  = (float*)d_ws;          // 6*K floats

    {
        dim3 grid((K + PBLOCK - 1) / PBLOCK);
        precompute_gauss<<<grid, PBLOCK, 0, stream>>>(pos_raw, conc_raw, scale_raw,
                                                      rot_raw, map_size,
                                                      gF, out, K, R);
    }
    {
        dim3 grid(R / (BLOCK * IPT), (K + SLICE - 1) / SLICE);
        splat_main<<<grid, BLOCK, 0, stream>>>(p_rays, u_rays, gF, out, K);
    }
}

// Round 8
// 21.027 us; speedup vs baseline: 1.0948x; 1.0573x over previous
//
#include <hip/hip_runtime.h>
#include <hip/hip_bf16.h>

#define EPS 1e-07f

#define BLOCK 1024
#define RPB   32            // rays per block (one wave-half per K-chunk)
#define NW    (BLOCK/64)    // 16 waves

// sqrt(0.5*log2(e)) ; log2(sqrt(2*pi))
#define SQRT_HALF_LOG2E 0.84932180028801904f
#define LOG2_SQRT_2PI   1.32574806473616588f

typedef float v4f __attribute__((ext_vector_type(4)));

// ---------------------------------------------------------------------------
// Single fused kernel.
//  grid.x = R/RPB blocks, 1024 threads (16 waves).
//  Each block handles 32 rays over ALL K Gaussians in 2 passes of K/2:
//   phase 1: block precomputes K/2 Gaussian records into LDS (redundant
//            across blocks, cheap hw-intrinsic math, ~2 per thread).
//            Record (6 floats): m00' m01' m11' (S/detS), cc, pos0, pos1
//            via cross-product identity  c0 - b^2/a = (u x (p-pos))^2 / a'.
//   phase 2: wave w, half h walks chunk c=(w<<1)|h: 64 Gaussians in 16
//            4-Gaussian groups; LDS reads have 2 distinct addrs/wave (free).
//  Reduction: shfl_xor(32) + [16][32] LDS tree; plain store. No atomics,
//  no zero pass, no workspace, one dispatch.
// ---------------------------------------------------------------------------
__global__ __launch_bounds__(BLOCK) void fused_splat(
        const float* __restrict__ pos_raw,
        const float* __restrict__ conc_raw,
        const float* __restrict__ scale_raw,
        const float* __restrict__ rot_raw,
        const void*  __restrict__ map_size_p,
        const float* __restrict__ p_rays,
        const float* __restrict__ u_rays,
        float* __restrict__ out,
        int K, int R)
{
    // K/2 = 2048 Gaussians per pass -> 512 groups -> 48 KB
    __shared__ float sG[512][6][4];
    __shared__ float psum[NW][RPB];

    const int tid  = threadIdx.x;
    const int lane = tid & 63;
    const int wv   = tid >> 6;          // 0..15
    const int rayl = lane & 31;         // ray within block
    const int half = lane >> 5;         // 0/1
    const int chunk = (wv << 1) | half; // 0..31

    int ray = blockIdx.x * RPB + rayl;
    if (ray >= R) ray = R - 1;          // defensive (R % RPB == 0 normally)

    // map_size may arrive as int32 or float32 single-element array.
    unsigned int msbits = *(const unsigned int*)map_size_p;
    float msf = __uint_as_float(msbits);
    const float ms = (msf >= 1e-3f && msf <= 1e9f) ? msf
                                                   : (float)(*(const int*)map_size_p);

    // Per-ray coefficients.
    float2 p2 = *(const float2*)(p_rays + 2*ray);
    float2 u2 = *(const float2*)(u_rays + 2*ray);
    const float p0 = p2.x, p1 = p2.y, u0 = u2.x, u1 = u2.y;
    const float qu0  = u0*u0, qu1 = 2.0f*u0*u1, qu2 = u1*u1;
    const float wt   =  SQRT_HALF_LOG2E * (u0*p1 - u1*p0);
    const float su1  =  SQRT_HALF_LOG2E * u1;
    const float nsu0 = -SQRT_HALF_LOG2E * u0;

    float acc = 0.0f;

    const int KH = K >> 1;              // Gaussians per pass (2048)
    const int CL = KH >> 5;             // chunk length (64)
    const int NG = CL >> 2;             // groups per chunk (16)

    for (int pass = 0; pass < 2; ++pass) {
        const int kbase = pass * KH;

        __syncthreads();                // previous pass fully consumed

        // ---- phase 1: precompute this pass's Gaussians into LDS ----
        for (int k = tid; k < KH; k += BLOCK) {
            const int kg = kbase + k;

            float pr0 = pos_raw[2*kg], pr1 = pos_raw[2*kg+1];
            float pos0 = ms / (1.0f + __expf(-pr0));
            float pos1 = ms / (1.0f + __expf(-pr1));

            float cr = conc_raw[kg];
            float conc = fmaxf(cr, 0.0f) + __logf(1.0f + __expf(-fabsf(cr)));

            float s0 = __expf(scale_raw[2*kg]);
            float s1 = __expf(scale_raw[2*kg+1]);
            float d0 = 1.0f / (s0*s0 + EPS);
            float d1 = 1.0f / (s1*s1 + EPS);

            float rot = rot_raw[kg];
            float c = __cosf(rot), s = __sinf(rot);

            float m00 = c*c*d0 + s*s*d1;
            float m01 = c*s*(d0 - d1);
            float m11 = s*s*d0 + c*c*d1;

            float det    = d0 * d1;
            float invdet = 1.0f / det;
            float cc = __log2f(conc) + LOG2_SQRT_2PI - 0.5f * __log2f(det);

            const int q = k >> 2, e = k & 3;
            sG[q][0][e] = m00 * invdet;
            sG[q][1][e] = m01 * invdet;
            sG[q][2][e] = m11 * invdet;
            sG[q][3][e] = cc;
            sG[q][4][e] = pos0;
            sG[q][5][e] = pos1;
        }
        __syncthreads();

        // ---- phase 2: walk this wave-half's chunk ----
        const int g0 = chunk * NG;
        #pragma unroll 4
        for (int gq = 0; gq < NG; ++gq) {
            const int t4 = g0 + gq;
            v4f M00 = *(const v4f*)&sG[t4][0][0];
            v4f M01 = *(const v4f*)&sG[t4][1][0];
            v4f M11 = *(const v4f*)&sG[t4][2][0];
            v4f CC  = *(const v4f*)&sG[t4][3][0];
            v4f P0  = *(const v4f*)&sG[t4][4][0];
            v4f P1  = *(const v4f*)&sG[t4][5][0];

            #pragma unroll
            for (int g = 0; g < 4; ++g) {
                float a_  = fmaf(qu2, M11[g], fmaf(qu1, M01[g], qu0 * M00[g]));
                float cr_ = fmaf(nsu0, P1[g], fmaf(su1, P0[g], wt));
                float ra_ = __builtin_amdgcn_rsqf(a_);
                float t_  = cr_ * ra_;
                float ar_ = fmaf(-t_, t_, CC[g]);
                float e_  = __builtin_amdgcn_exp2f(ar_);
                acc = fmaf(ra_, e_, acc);
            }
        }
    }

    // ---- reduction: 32 partials per ray -> one value ----
    acc += __shfl_xor(acc, 32, 64);          // merge the two halves
    if (half == 0) psum[wv][rayl] = acc;
    __syncthreads();

    if (wv == 0 && lane < RPB) {
        float s = 0.0f;
        #pragma unroll
        for (int w = 0; w < NW; ++w) s += psum[w][lane];
        int oray = blockIdx.x * RPB + lane;
        if (oray < R) out[oray] = s;
    }
}

// ---------------------------------------------------------------------------
extern "C" void kernel_launch(void* const* d_in, const int* in_sizes, int n_in,
                              void* d_out, int out_size, void* d_ws, size_t ws_size,
                              hipStream_t stream)
{
    const float* pos_raw   = (const float*)d_in[0];
    const float* conc_raw  = (const float*)d_in[1];
    const float* scale_raw = (const float*)d_in[2];
    const float* rot_raw   = (const float*)d_in[3];
    const float* p_rays    = (const float*)d_in[4];
    const float* u_rays    = (const float*)d_in[5];
    const void*  map_size  = d_in[6];

    const int K = in_sizes[1];          // conc_raw is (K,)
    const int R = out_size;             // output is (R,)

    float* out = (float*)d_out;

    dim3 grid((R + RPB - 1) / RPB);     // 256 blocks for R=8192
    fused_splat<<<grid, BLOCK, 0, stream>>>(pos_raw, conc_raw, scale_raw,
                                            rot_raw, map_size,
                                            p_rays, u_rays, out, K, R);
}